// Round 4
// baseline (520.762 us; speedup 1.0000x reference)
//
#include <hip/hip_runtime.h>

// Correlation (FlowNet-style), kernel=1, stride=1, md=pad=4.
// B=8, C=128, H=W=192 -> out [8, 81, 192, 192] fp32.
//
// Round-4: LDS staging with lane-contiguous b128 reads + global_load_lds
// double-buffered pipeline.
//  - 1152 blocks (8b x 6xt x 24yt), tile 8y x 32x, 576 thr = 9 waves,
//    wave w = dy. Thread: 4 x-px, acc[9 dx][4].
//  - LDS per channel block (1024 floats): [X1 8x32 | X2M 16x32 | X2L 16x8 | X2R 16x8]
//    CB=8 channels/chunk -> 32 KB/buffer, x2 double-buffered = 64 KB.
//  - reads: X1 at 16B*lane (contiguous); X2M rows stride 128B -> window reads
//    k=0..2 are contiguous 1024B wave-blocks; edge lanes (tx==0/7) read the
//    halo arrays (32B row stride -> their bank quads = the ones the main
//    read's holes free up). All reads minimum-time by construction.
//  - staging: global_load_lds width=16 for X1/X2M (per-lane src, OOB rows
//    redirected to a zeroed 256B region of d_ws); halo reg-staged (256 thr).
//  - pipeline: issue(t+1) right after the one barrier per chunk; loads fly
//    under the ~650-cycle compute phase.

#define NT 576

__device__ __forceinline__ void gl_lds16(const float* g, float* l) {
  __builtin_amdgcn_global_load_lds(
      (const __attribute__((address_space(1))) void*)(g),
      (__attribute__((address_space(3))) void*)(l), 16, 0, 0);
}

__global__ __launch_bounds__(NT)
void corr_kernel(const float* __restrict__ x1g, const float* __restrict__ x2g,
                 float* __restrict__ outg, const float* __restrict__ zp) {
  constexpr int Cc = 128, Hh = 192, Ww = 192, HW = Hh * Ww;
  constexpr int CB = 8, NCK = Cc / CB;   // 8 channels/chunk, 16 chunks
  constexpr int CCB = 1024;              // floats per channel block
  constexpr int BUFF = CB * CCB;         // 8192 floats per buffer
  constexpr int CADV = CB * HW;          // global src advance per chunk

  __shared__ __align__(16) float lds[2 * BUFF];  // 64 KB

  const int bid  = blockIdx.x;
  const int tile = (bid & 7) * 144 + (bid >> 3);  // XCD-chunked, yt fastest
  const int yt = tile % 24;
  const int t2 = tile / 24;
  const int xt = t2 % 6;
  const int b  = t2 / 6;
  const int y0 = yt * 8, x0 = xt * 32;

  const int tid  = (int)threadIdx.x;
  const int w    = tid >> 6;   // dy = w (0..8)
  const int lane = tid & 63;
  const int tx   = lane & 7;
  const int ty   = lane >> 3;
  const int rw   = ty + w;     // x2 window row index 0..15

  // ---- staging descriptors (computed once) ----
  // X1: 512 slots; wave k stages channel k. dst = cc*CCB + 4*(tid&63).
  const bool hasA = (tid < 512);
  const int offA = ((tid >> 6) * CCB) + 4 * (tid & 63);
  const float* srcA =
      x1g + (((size_t)(b * Cc + (tid >> 6)) * Hh + (y0 + ((tid >> 3) & 7))) * Ww +
             x0 + 4 * (tid & 7));

  // X2M slot 0 (all 576 threads): i = tid
  const int cc0 = tid >> 7, rr0 = (tid >> 3) & 15, qq0 = tid & 7;
  const int gy0 = y0 + rr0 - 4;
  const bool ok0 = (gy0 >= 0) && (gy0 < Hh);
  const int offM0 = cc0 * CCB + 256 + 4 * (tid & 127);
  const float* srcM0 =
      x2g + (((size_t)(b * Cc + cc0) * Hh + (ok0 ? gy0 : 0)) * Ww + x0 + 4 * qq0);

  // X2M slot 1: i = tid + 576 (valid while < 1024 -> waves 0..6)
  const int j1 = tid + NT;
  const bool hasM1 = (j1 < 1024);
  const int cc1 = j1 >> 7, rr1 = (j1 >> 3) & 15, qq1 = j1 & 7;
  const int gy1 = y0 + rr1 - 4;
  const bool ok1 = (gy1 >= 0) && (gy1 < Hh);
  const int offM1 = cc1 * CCB + 256 + 4 * (j1 & 127);
  const float* srcM1 =
      x2g + (((size_t)(b * Cc + cc1) * Hh + (ok1 ? gy1 : 0)) * Ww + x0 + 4 * qq1);

  // halo (reg-staged): tid<128 -> left (cols x0-4..x0-1), 128..255 -> right
  const bool hasLR = (tid < 256);
  const bool isR = (tid >= 128);
  const int iLR = tid & 127;
  const int ccL = iLR >> 4, rrL = iLR & 15;
  const int gyL = y0 + rrL - 4;
  const int gxL = isR ? (x0 + 32) : (x0 - 4);
  const bool okLR =
      hasLR && (gyL >= 0) && (gyL < Hh) && (gxL >= 0) && (gxL + 3 < Ww);
  const int offLR = ccL * CCB + (isR ? 896 : 768) + 8 * rrL;
  const float* srcLR =
      x2g + (((size_t)(b * Cc + ccL) * Hh + ((gyL >= 0 && gyL < Hh) ? gyL : 0)) * Ww +
             (okLR ? gxL : 0));

  const float4 f4z = make_float4(0.f, 0.f, 0.f, 0.f);
  float4 pLR = f4z;

  auto issue = [&](int bufbase) {
    if (hasLR) pLR = okLR ? *(const float4*)srcLR : f4z;
    if (hasA)  gl_lds16(srcA, &lds[bufbase + offA]);
    gl_lds16(ok0 ? srcM0 : zp, &lds[bufbase + offM0]);
    if (hasM1) gl_lds16(ok1 ? srcM1 : zp, &lds[bufbase + offM1]);
    srcA += CADV; srcM0 += CADV; srcM1 += CADV; srcLR += CADV;
  };

  // ---- compute-side LDS offsets (floats) ----
  const int oA   = 4 * lane;                    // X1, contiguous 16B*lane
  const int oM1r = 256 + rw * 32 + 4 * tx;      // window cols 0..3 (k=1)
  const int oM0r = (tx == 0) ? (768 + rw * 8) : (oM1r - 4);   // k=0
  const int oM2r = (tx == 7) ? (896 + rw * 8) : (oM1r + 4);   // k=2

  float acc[9][4];
#pragma unroll
  for (int d = 0; d < 9; ++d)
#pragma unroll
    for (int q = 0; q < 4; ++q) acc[d][q] = 0.f;

  issue(0);  // prefetch chunk 0 into buffer 0

#pragma unroll 2
  for (int ck = 0; ck < NCK; ++ck) {
    const int B0 = (ck & 1) * BUFF;
    if (hasLR) *(float4*)&lds[B0 + offLR] = pLR;  // publish halo for chunk ck
    __syncthreads();  // drains vmcnt (global_load_lds) + makes halo visible
    if (ck + 1 < NCK) issue(((ck + 1) & 1) * BUFF);  // fly under compute

#pragma unroll
    for (int cc = 0; cc < CB; ++cc) {
      const float4 a  = *(const float4*)&lds[B0 + cc * CCB + oA];
      const float4 r0 = *(const float4*)&lds[B0 + cc * CCB + oM0r];
      const float4 r1 = *(const float4*)&lds[B0 + cc * CCB + oM1r];
      const float4 r2 = *(const float4*)&lds[B0 + cc * CCB + oM2r];
      const float av[4] = {a.x, a.y, a.z, a.w};
      const float rv[12] = {r0.x, r0.y, r0.z, r0.w, r1.x, r1.y, r1.z, r1.w,
                            r2.x, r2.y, r2.z, r2.w};
#pragma unroll
      for (int dx = 0; dx < 9; ++dx)
#pragma unroll
        for (int q = 0; q < 4; ++q)
          acc[dx][q] += av[q] * rv[dx + q];
    }
  }

  // ---- epilogue: out[b][w*9+dx][y0+ty][x0+4tx .. +3] ----
  const float invc = 1.0f / 128.0f;
  const int y = y0 + ty, xb = x0 + 4 * tx;
#pragma unroll
  for (int dx = 0; dx < 9; ++dx) {
    float4 o;
    o.x = acc[dx][0] * invc;
    o.y = acc[dx][1] * invc;
    o.z = acc[dx][2] * invc;
    o.w = acc[dx][3] * invc;
    const size_t oidx = (((size_t)b * 81 + (w * 9 + dx)) * Hh + y) * Ww + xb;
    *(float4*)&outg[oidx] = o;
  }
}

extern "C" void kernel_launch(void* const* d_in, const int* in_sizes, int n_in,
                              void* d_out, int out_size, void* d_ws, size_t ws_size,
                              hipStream_t stream) {
  const float* x1 = (const float*)d_in[0];
  const float* x2 = (const float*)d_in[1];
  float* out = (float*)d_out;
  // zero page for OOB global_load_lds sources (d_ws is poisoned, zero it)
  hipMemsetAsync(d_ws, 0, 256, stream);
  corr_kernel<<<dim3(1152), dim3(NT), 0, stream>>>(x1, x2, out,
                                                   (const float*)d_ws);
}